// Round 5
// baseline (837.523 us; speedup 1.0000x reference)
//
#include <hip/hip_runtime.h>
#include <hip/hip_bf16.h>
#include <math.h>

#define VOCAB 50000
#define EMB 100
#define HID 128
#define NPROD 10000
#define PEMB 50
#define BSZ 256
#define TLEN 512
#define INDIM 150
#define G4 512  // 4*HID

typedef __attribute__((ext_vector_type(4))) float f32x4;

__device__ __forceinline__ float sigm(float x) {
    // x<<0: expf->inf, rcp(inf)=0 (correct). x>>0: expf->0, rcp(1)=1 (correct).
    return __builtin_amdgcn_rcpf(1.f + __expf(-x));
}
__device__ __forceinline__ float tanh_fast(float x) {
    float e = __expf(-2.f * fabsf(x));          // in [0,1], never overflows
    float r = (1.f - e) * __builtin_amdgcn_rcpf(1.f + e);
    return __builtin_copysignf(r, x);
}

// ---------------- K0: transpose W_ih [512][150] -> Wt [150][512] ----------------
__global__ void k_transpose(const float* __restrict__ W_ih, float* __restrict__ Wt) {
    int idx = blockIdx.x * blockDim.x + threadIdx.x;
    if (idx < INDIM * G4) {
        int d = idx / G4, g = idx % G4;
        Wt[idx] = W_ih[g * INDIM + d];  // coalesced write
    }
}

// ---------------- K1: pbias[b][g] = b_ih+b_hh + pemb[product[b]] . W_ih[:,100:] ----------------
__global__ void k_pbias(const int* __restrict__ product,
                        const float* __restrict__ pemb,
                        const float* __restrict__ Wt,
                        const float* __restrict__ b_ih,
                        const float* __restrict__ b_hh,
                        float* __restrict__ pbias) {
    __shared__ float ep_s[PEMB];
    int b = blockIdx.x;
    int tid = threadIdx.x;
    int p = product[b];
    if (tid < PEMB) ep_s[tid] = pemb[p * PEMB + tid];
    __syncthreads();
    int g0 = tid, g1 = tid + 256;
    float a0 = b_ih[g0] + b_hh[g0];
    float a1 = b_ih[g1] + b_hh[g1];
    #pragma unroll 5
    for (int d = 0; d < PEMB; ++d) {
        float e = ep_s[d];
        a0 += e * Wt[(EMB + d) * G4 + g0];
        a1 += e * Wt[(EMB + d) * G4 + g1];
    }
    pbias[b * G4 + g0] = a0;
    pbias[b * G4 + g1] = a1;
}

// ---------------- K2: table[v][g] = emb[v][:] . W_ih[g][:100] ----------------
__global__ void k_table(const float* __restrict__ emb,
                        const float* __restrict__ Wt,
                        float* __restrict__ table) {
    __shared__ __align__(16) float es[16 * EMB];
    int v0 = blockIdx.x * 16;
    int tid = threadIdx.x;
    for (int l = tid; l < 16 * EMB; l += 256) es[l] = emb[v0 * EMB + l];
    __syncthreads();
    float acc0[16], acc1[16];
    #pragma unroll
    for (int r = 0; r < 16; ++r) { acc0[r] = 0.f; acc1[r] = 0.f; }
    #pragma unroll 5
    for (int k4 = 0; k4 < EMB / 4; ++k4) {
        float w0[4], w1[4];
        #pragma unroll
        for (int j = 0; j < 4; ++j) {
            w0[j] = Wt[(k4 * 4 + j) * G4 + tid];
            w1[j] = Wt[(k4 * 4 + j) * G4 + tid + 256];
        }
        #pragma unroll
        for (int r = 0; r < 16; ++r) {
            float4 e = *reinterpret_cast<const float4*>(&es[r * EMB + k4 * 4]);
            acc0[r] += e.x * w0[0] + e.y * w0[1] + e.z * w0[2] + e.w * w0[3];
            acc1[r] += e.x * w1[0] + e.y * w1[1] + e.z * w1[2] + e.w * w1[3];
        }
    }
    #pragma unroll
    for (int r = 0; r < 16; ++r) {
        table[(v0 + r) * G4 + tid]       = acc0[r];
        table[(v0 + r) * G4 + tid + 256] = acc1[r];
    }
}

// ---------------- K3: per-batch-row LSTM ----------------
// 256 blocks x 1024 threads (16 waves). Thread t: g = t>>1, half = t&1 —
// owns HALF a W_hh gate row (64 f32, VGPR-resident without allocator pressure).
// Pair combine via __shfl_xor(a,1) (quad DPP). h read from LDS as wave
// broadcast (2 distinct addrs/wave = free 2-way). Nonlinearity wave-uniform.
// c/h update on waves 0-1 only. 2 barriers/step.
__global__ __launch_bounds__(1024, 4) void k_lstm(
    const int* __restrict__ review,
    const float* __restrict__ W_hh,
    const float* __restrict__ table,
    const float* __restrict__ pbias,
    const float* __restrict__ fc_w,
    const float* __restrict__ fc_b,
    float* __restrict__ out) {
    __shared__ __align__(16) float hsA[HID];
    __shared__ __align__(16) float hsB[HID];
    __shared__ float gsh[G4];
    __shared__ int rv_s[TLEN];
    int b = blockIdx.x;
    int t0 = threadIdx.x;
    int g = t0 >> 1;       // gate row 0..511
    int half = t0 & 1;     // K-half
    int wgate = g >> 7;    // 0=i 1=f 2=g 3=o — wave-uniform (g spans 32 per wave)

    if (t0 < TLEN) rv_s[t0] = review[b * TLEN + t0];
    if (t0 < HID) { hsA[t0] = 0.f; hsB[t0] = 0.f; }
    __syncthreads();

    float x_cur = table[rv_s[0] * G4 + g];   // coalesced row gather
    float pb = pbias[b * G4 + g];

    // half gate row -> 16 f32x4 in VGPRs (demand ~90 < 128 cap at 4 waves/SIMD)
    f32x4 w4[16];
    const float* wrow = W_hh + g * HID + half * 64;
    #pragma unroll
    for (int j = 0; j < 16; ++j)
        w4[j] = *reinterpret_cast<const f32x4*>(wrow + 4 * j);
    #pragma unroll
    for (int j = 0; j < 16; ++j) asm volatile("" : "+v"(w4[j]));

    const float* hr = hsA;
    float* hw = hsB;
    float c = 0.f;

    for (int t = 0; t < TLEN; ++t) {
        float x_next = table[rv_s[(t + 1) & (TLEN - 1)] * G4 + g];  // prefetch

        float a0 = 0.f, a1 = 0.f, a2 = 0.f, a3 = 0.f;
        const float* hb = hr + half * 64;
        #pragma unroll
        for (int j = 0; j < 16; ++j) {
            f32x4 h4 = *reinterpret_cast<const f32x4*>(hb + 4 * j);  // LDS broadcast
            a0 += h4.x * w4[j].x;
            a1 += h4.y * w4[j].y;
            a2 += h4.z * w4[j].z;
            a3 += h4.w * w4[j].w;
        }
        float a = (a0 + a1) + (a2 + a3);
        a += __shfl_xor(a, 1);               // combine K-halves (intra-quad)
        float pre = x_cur + pb + a;
        float act = (wgate == 2) ? tanh_fast(pre) : sigm(pre);
        gsh[g] = act;                        // both halves write same value: benign
        __syncthreads();

        if (t0 < HID) {                      // waves 0-1 only, wave-uniform branch
            float gi = gsh[t0];
            float gf = gsh[HID + t0];
            float gg = gsh[2 * HID + t0];
            float go = gsh[3 * HID + t0];
            c = gf * c + gi * gg;
            hw[t0] = go * tanh_fast(c);
        }
        __syncthreads();

        const float* tmp = hr; hr = hw; hw = (float*)tmp;
        x_cur = x_next;
    }

    // fused FC + sigmoid (hr holds h_T after final swap)
    if (t0 < 64) {
        float v = hr[t0] * fc_w[t0] + hr[t0 + 64] * fc_w[t0 + 64];
        #pragma unroll
        for (int off = 32; off >= 1; off >>= 1) v += __shfl_xor(v, off);
        if (t0 == 0) out[b] = sigm(v + fc_b[0]);
    }
}

extern "C" void kernel_launch(void* const* d_in, const int* in_sizes, int n_in,
                              void* d_out, int out_size, void* d_ws, size_t ws_size,
                              hipStream_t stream) {
    const int*   review  = (const int*)d_in[0];
    const int*   product = (const int*)d_in[1];
    const float* emb     = (const float*)d_in[2];
    const float* pemb    = (const float*)d_in[3];
    const float* W_ih    = (const float*)d_in[4];
    const float* W_hh    = (const float*)d_in[5];
    const float* b_ih    = (const float*)d_in[6];
    const float* b_hh    = (const float*)d_in[7];
    const float* fc_w    = (const float*)d_in[8];
    const float* fc_b    = (const float*)d_in[9];
    float* out = (float*)d_out;

    char* ws = (char*)d_ws;
    float* Wt    = (float*)(ws);                       // 150*512*4   = 307200 B
    float* pbias = (float*)(ws + 307200);              // 256*512*4   = 524288 B
    float* table = (float*)(ws + 831488);              // 50000*512*4 = 102.4 MB

    k_transpose<<<(INDIM * G4 + 255) / 256, 256, 0, stream>>>(W_ih, Wt);
    k_pbias<<<BSZ, 256, 0, stream>>>(product, pemb, Wt, b_ih, b_hh, pbias);
    k_table<<<VOCAB / 16, 256, 0, stream>>>(emb, Wt, table);
    k_lstm<<<BSZ, 1024, 0, stream>>>(review, W_hh, table, pbias, fc_w, fc_b, out);
}

// Round 8
// 643.304 us; speedup vs baseline: 1.3019x; 1.3019x over previous
//
#include <hip/hip_runtime.h>
#include <hip/hip_bf16.h>
#include <math.h>

#define VOCAB 50000
#define EMB 100
#define HID 128
#define NPROD 10000
#define PEMB 50
#define BSZ 256
#define TLEN 512
#define INDIM 150
#define G4 512  // 4*HID

typedef __attribute__((ext_vector_type(4))) float f32x4;

__device__ __forceinline__ float sigm(float x) {
    // x<<0: expf->inf, rcp(inf)=0 (correct). x>>0: expf->0, rcp(1)=1 (correct).
    return __builtin_amdgcn_rcpf(1.f + __expf(-x));
}
__device__ __forceinline__ float tanh_fast(float x) {
    float e = __expf(-2.f * fabsf(x));          // in [0,1], never overflows
    float r = (1.f - e) * __builtin_amdgcn_rcpf(1.f + e);
    return __builtin_copysignf(r, x);
}

// ---------------- K0: transpose W_ih [512][150] -> Wt [150][512] ----------------
__global__ void k_transpose(const float* __restrict__ W_ih, float* __restrict__ Wt) {
    int idx = blockIdx.x * blockDim.x + threadIdx.x;
    if (idx < INDIM * G4) {
        int d = idx / G4, g = idx % G4;
        Wt[idx] = W_ih[g * INDIM + d];  // coalesced write
    }
}

// ---------------- K1: pbias[b][g] = b_ih+b_hh + pemb[product[b]] . W_ih[:,100:] ----------------
__global__ void k_pbias(const int* __restrict__ product,
                        const float* __restrict__ pemb,
                        const float* __restrict__ Wt,
                        const float* __restrict__ b_ih,
                        const float* __restrict__ b_hh,
                        float* __restrict__ pbias) {
    __shared__ float ep_s[PEMB];
    int b = blockIdx.x;
    int tid = threadIdx.x;
    int p = product[b];
    if (tid < PEMB) ep_s[tid] = pemb[p * PEMB + tid];
    __syncthreads();
    int g0 = tid, g1 = tid + 256;
    float a0 = b_ih[g0] + b_hh[g0];
    float a1 = b_ih[g1] + b_hh[g1];
    #pragma unroll 5
    for (int d = 0; d < PEMB; ++d) {
        float e = ep_s[d];
        a0 += e * Wt[(EMB + d) * G4 + g0];
        a1 += e * Wt[(EMB + d) * G4 + g1];
    }
    pbias[b * G4 + g0] = a0;
    pbias[b * G4 + g1] = a1;
}

// ---------------- K2: table[v][g] = emb[v][:] . W_ih[g][:100] ----------------
__global__ void k_table(const float* __restrict__ emb,
                        const float* __restrict__ Wt,
                        float* __restrict__ table) {
    __shared__ __align__(16) float es[16 * EMB];
    int v0 = blockIdx.x * 16;
    int tid = threadIdx.x;
    for (int l = tid; l < 16 * EMB; l += 256) es[l] = emb[v0 * EMB + l];
    __syncthreads();
    float acc0[16], acc1[16];
    #pragma unroll
    for (int r = 0; r < 16; ++r) { acc0[r] = 0.f; acc1[r] = 0.f; }
    #pragma unroll 5
    for (int k4 = 0; k4 < EMB / 4; ++k4) {
        float w0[4], w1[4];
        #pragma unroll
        for (int j = 0; j < 4; ++j) {
            w0[j] = Wt[(k4 * 4 + j) * G4 + tid];
            w1[j] = Wt[(k4 * 4 + j) * G4 + tid + 256];
        }
        #pragma unroll
        for (int r = 0; r < 16; ++r) {
            float4 e = *reinterpret_cast<const float4*>(&es[r * EMB + k4 * 4]);
            acc0[r] += e.x * w0[0] + e.y * w0[1] + e.z * w0[2] + e.w * w0[3];
            acc1[r] += e.x * w1[0] + e.y * w1[1] + e.z * w1[2] + e.w * w1[3];
        }
    }
    #pragma unroll
    for (int r = 0; r < 16; ++r) {
        table[(v0 + r) * G4 + tid]       = acc0[r];
        table[(v0 + r) * G4 + tid + 256] = acc1[r];
    }
}

// ---------------- K3: per-batch-row LSTM, thread g owns one full gate row ----------------
// 256 blocks x 512 threads. Thread g: W_hh row g (128 f32) VGPR-resident.
// amdgpu_waves_per_eu(2,2): pins the allocator's occupancy target to 2 waves/EU
// -> 256-VGPR budget -> no AGPR migration of the weight array (r3/r5 failure mode).
// Dot reads h via LDS broadcast (all lanes same addr, conflict-free). Nonlinearity
// wave-uniform (g>>7). 2 barriers/step.
__global__ void
__attribute__((amdgpu_flat_work_group_size(512, 512), amdgpu_waves_per_eu(2, 2)))
k_lstm(
    const int* __restrict__ review,
    const float* __restrict__ W_hh,
    const float* __restrict__ table,
    const float* __restrict__ pbias,
    const float* __restrict__ fc_w,
    const float* __restrict__ fc_b,
    float* __restrict__ out) {
    __shared__ __align__(16) float hsA[HID];
    __shared__ __align__(16) float hsB[HID];
    __shared__ float gsh[G4];
    __shared__ int rv_s[TLEN];
    int b = blockIdx.x;
    int g = threadIdx.x;
    int wgate = g >> 7;   // 0=i 1=f 2=g 3=o, wave-uniform
    int u = g & 127;

    rv_s[g] = review[b * TLEN + g];
    if (g < HID) { hsA[g] = 0.f; hsB[g] = 0.f; }
    __syncthreads();

    // issue first x-gather early (coalesced 2KB row)
    float x_cur = table[rv_s[0] * G4 + g];
    float pb = pbias[b * G4 + g];

    // W_hh row g -> 128 VGPRs, pinned against rematerialization
    float w[128];
    #pragma unroll
    for (int j = 0; j < 32; ++j) {
        f32x4 t = *reinterpret_cast<const f32x4*>(W_hh + g * HID + 4 * j);
        w[4 * j + 0] = t.x; w[4 * j + 1] = t.y; w[4 * j + 2] = t.z; w[4 * j + 3] = t.w;
    }
    #pragma unroll
    for (int k = 0; k < 128; ++k) asm volatile("" : "+v"(w[k]));

    const float* hr = hsA;
    float* hw = hsB;
    float c = 0.f;

    for (int t = 0; t < TLEN; ++t) {
        // prefetch next step's x row (consumed after the barrier next iteration)
        float x_next = table[rv_s[(t + 1) & (TLEN - 1)] * G4 + g];

        float a0 = 0.f, a1 = 0.f, a2 = 0.f, a3 = 0.f;
        #pragma unroll
        for (int j = 0; j < 32; ++j) {
            f32x4 h4 = *reinterpret_cast<const f32x4*>(&hr[4 * j]);  // wave broadcast
            a0 += h4.x * w[4 * j + 0];
            a1 += h4.y * w[4 * j + 1];
            a2 += h4.z * w[4 * j + 2];
            a3 += h4.w * w[4 * j + 3];
        }
        float pre = x_cur + pb + ((a0 + a1) + (a2 + a3));
        float act = (wgate == 2) ? tanh_fast(pre) : sigm(pre);
        gsh[g] = act;
        __syncthreads();

        // every thread computes its unit's c,h redundantly (identical across replicas)
        float gi = gsh[u];
        float gf = gsh[HID + u];
        float gg = gsh[2 * HID + u];
        float go = gsh[3 * HID + u];
        c = gf * c + gi * gg;
        float h = go * tanh_fast(c);
        if (g < HID) hw[g] = h;
        __syncthreads();

        const float* tmp = hr; hr = hw; hw = (float*)tmp;
        x_cur = x_next;
    }

    // fused FC + sigmoid (hr holds h_T after final swap)
    if (g < 64) {
        float v = hr[g] * fc_w[g] + hr[g + 64] * fc_w[g + 64];
        #pragma unroll
        for (int off = 32; off >= 1; off >>= 1) v += __shfl_xor(v, off);
        if (g == 0) out[b] = sigm(v + fc_b[0]);
    }
}

extern "C" void kernel_launch(void* const* d_in, const int* in_sizes, int n_in,
                              void* d_out, int out_size, void* d_ws, size_t ws_size,
                              hipStream_t stream) {
    const int*   review  = (const int*)d_in[0];
    const int*   product = (const int*)d_in[1];
    const float* emb     = (const float*)d_in[2];
    const float* pemb    = (const float*)d_in[3];
    const float* W_ih    = (const float*)d_in[4];
    const float* W_hh    = (const float*)d_in[5];
    const float* b_ih    = (const float*)d_in[6];
    const float* b_hh    = (const float*)d_in[7];
    const float* fc_w    = (const float*)d_in[8];
    const float* fc_b    = (const float*)d_in[9];
    float* out = (float*)d_out;

    char* ws = (char*)d_ws;
    float* Wt    = (float*)(ws);                       // 150*512*4   = 307200 B
    float* pbias = (float*)(ws + 307200);              // 256*512*4   = 524288 B
    float* table = (float*)(ws + 831488);              // 50000*512*4 = 102.4 MB

    k_transpose<<<(INDIM * G4 + 255) / 256, 256, 0, stream>>>(W_ih, Wt);
    k_pbias<<<BSZ, 256, 0, stream>>>(product, pemb, Wt, b_ih, b_hh, pbias);
    k_table<<<VOCAB / 16, 256, 0, stream>>>(emb, Wt, table);
    k_lstm<<<BSZ, 512, 0, stream>>>(review, W_hh, table, pbias, fc_w, fc_b, out);
}